// Round 21
// baseline (65.313 us; speedup 1.0000x reference)
//
#include <hip/hip_runtime.h>

// ---------------------------------------------------------------------------
// MixModel R21: 128-row tiles, 384 thr (6 waves), PER-WAVE staging (no
// barrier1), separate obuf, single barrier2 + flat NT tail.
// Ladder: R10 71.1 | R16 +NT 65.3 | R17 row-pair pk 65.2 | R18 LDS-out 62.0
//   | R19 sep-obuf 59.8 (BEST) | R20 per-wave staging @3w 60.5 (neutral).
// Theory: R19 retires 260 blocks/us (1us-life blocks) — possible CP dispatch
// limit. R13 (384thr) lost via 6-wave barrier1+drain coupling; that barrier
// is now deleted (R20 technique): wave wid stages f4 [18*rpmin..18*rpmax+17]
// itself (bases {0,180,378,576,756,896}, 4 loads, overlaps benign) and waits
// only its own vmcnt. Block count halves -> 130 blocks/us.
// n=1e6 not divisible by 128: clamp brow=min(bid*128, n-128); 64-row overlap
// computed twice with identical values (deterministic, NT-safe).
// Tripwires: VGPR>56 or WRITE>>141MB -> revert to R19.
// ---------------------------------------------------------------------------

typedef float f2 __attribute__((ext_vector_type(2)));
typedef float fv4 __attribute__((ext_vector_type(4)));

__device__ __forceinline__ f2 splat2(float x) { f2 v; v.x = x; v.y = x; return v; }
__device__ __forceinline__ f2 mk2(float a, float b) { f2 v; v.x = a; v.y = b; return v; }
__device__ __forceinline__ f2 fma2(f2 a, f2 b, f2 c) { return __builtin_elementwise_fma(a, b, c); }
__device__ __forceinline__ f2 relu2(f2 a) { return __builtin_elementwise_max(a, splat2(0.0f)); }

// Packed MLP 3->3->6->3 (pair-axis = 2 rows).
__device__ __forceinline__ void mlp_a2(f2 x0, f2 x1, f2 x2,
                                       const float* __restrict__ w0, const float* __restrict__ b0,
                                       const float* __restrict__ w1, const float* __restrict__ b1,
                                       const float* __restrict__ w2, const float* __restrict__ b2,
                                       f2& o0, f2& o1, f2& o2)
{
    f2 h0[3];
#pragma unroll
    for (int q = 0; q < 3; ++q) {
        f2 a = fma2(x0, splat2(w0[q*3+0]), splat2(b0[q]));
        a = fma2(x1, splat2(w0[q*3+1]), a);
        a = fma2(x2, splat2(w0[q*3+2]), a);
        h0[q] = relu2(a);
    }
    f2 h1[6];
#pragma unroll
    for (int q = 0; q < 6; ++q) {
        f2 a = fma2(h0[0], splat2(w1[q*3+0]), splat2(b1[q]));
        a = fma2(h0[1], splat2(w1[q*3+1]), a);
        a = fma2(h0[2], splat2(w1[q*3+2]), a);
        h1[q] = relu2(a);
    }
    f2 t[3];
#pragma unroll
    for (int q = 0; q < 3; ++q) {
        f2 a = fma2(h1[0], splat2(w2[q*6+0]), splat2(b2[q]));
#pragma unroll
        for (int i = 1; i < 6; ++i) a = fma2(h1[i], splat2(w2[q*6+i]), a);
        t[q] = a;
    }
    o0 = t[0]; o1 = t[1]; o2 = t[2];
}

// Packed MLP 4->4->6->2 (pair-axis = 2 rows).
__device__ __forceinline__ void mlp_b2(f2 x0, f2 x1, f2 x2, f2 x3,
                                       const float* __restrict__ w0, const float* __restrict__ b0,
                                       const float* __restrict__ w1, const float* __restrict__ b1,
                                       const float* __restrict__ w2, const float* __restrict__ b2,
                                       f2& o0, f2& o1)
{
    f2 h0[4];
#pragma unroll
    for (int q = 0; q < 4; ++q) {
        f2 a = fma2(x0, splat2(w0[q*4+0]), splat2(b0[q]));
        a = fma2(x1, splat2(w0[q*4+1]), a);
        a = fma2(x2, splat2(w0[q*4+2]), a);
        a = fma2(x3, splat2(w0[q*4+3]), a);
        h0[q] = relu2(a);
    }
    f2 h1[6];
#pragma unroll
    for (int q = 0; q < 6; ++q) {
        f2 a = fma2(h0[0], splat2(w1[q*4+0]), splat2(b1[q]));
        a = fma2(h0[1], splat2(w1[q*4+1]), a);
        a = fma2(h0[2], splat2(w1[q*4+2]), a);
        a = fma2(h0[3], splat2(w1[q*4+3]), a);
        h1[q] = relu2(a);
    }
    f2 t[2];
#pragma unroll
    for (int q = 0; q < 2; ++q) {
        f2 a = fma2(h1[0], splat2(w2[q*6+0]), splat2(b2[q]));
#pragma unroll
        for (int i = 1; i < 6; ++i) a = fma2(h1[i], splat2(w2[q*6+i]), a);
        t[q] = a;
    }
    o0 = t[0]; o1 = t[1];
}

#define ROWS_PB 128
#define TPB 384   // 6 waves; 128 rows = 64 row-pairs x 6 col-segments = 384

__global__ __launch_bounds__(TPB) void mixmodel_kernel(
    const float* __restrict__ u, const float* __restrict__ reg,
    const float* __restrict__ w10, const float* __restrict__ b10,
    const float* __restrict__ w11, const float* __restrict__ b11,
    const float* __restrict__ w12, const float* __restrict__ b12,
    const float* __restrict__ w20, const float* __restrict__ b20,
    const float* __restrict__ w21, const float* __restrict__ b21,
    const float* __restrict__ w22, const float* __restrict__ b22,
    const float* __restrict__ w30, const float* __restrict__ b30,
    const float* __restrict__ w31, const float* __restrict__ b31,
    const float* __restrict__ w32, const float* __restrict__ b32,
    float* __restrict__ out, int n)
{
    __shared__ float4 s4[ROWS_PB * 9];    // 18432 B input u-tile
    __shared__ float4 o4b[ROWS_PB * 9];   // 18432 B output tile
    __shared__ float  sreg[37];

    // clamp so the last (partial) tile re-covers the previous 64 rows:
    // overlap region computed twice with identical values — benign.
    const int brow = min((int)blockIdx.x * ROWS_PB, n - ROWS_PB);
    const int t    = threadIdx.x;
    const int wid  = t >> 6;
    const int lane = t & 63;

    // ---- per-wave DMA staging: wave wid needs f4 [18*rpmin, 18*rpmax+17]
    // rpmin=floor(64w/6): {0,10,21,32,42,53} -> exact bases {0,180,378,576,
    // 756,954}; 954 clamped to 896 so 4x64 loads stay in [0,1152).
    {
        const int rpmin = (64 * wid) / 6;
        const int bw = min(rpmin * 18, ROWS_PB * 9 - 256);
        const float4* __restrict__ g = reinterpret_cast<const float4*>(u + (size_t)brow * 36);
#pragma unroll
        for (int k = 0; k < 4; ++k) {
            const int base = bw + k * 64;          // f4 units, wave-uniform
            __builtin_amdgcn_global_load_lds(
                (const __attribute__((address_space(1))) void*)(g + base + lane),
                (__attribute__((address_space(3))) void*)(s4 + base),
                16, 0, 0);
        }
    }
    // sreg written redundantly by EACH wave (no cross-wave sync needed)
    if (lane < 37) sreg[lane] = reg[lane];

    // wave-local drain only — no block barrier before compute
    asm volatile("s_waitcnt vmcnt(0) lgkmcnt(0)" ::: "memory");
    __builtin_amdgcn_sched_barrier(0);

    const int rp = t / 6;              // row-pair 0..63 (rows 2rp, 2rp+1)
    const int s  = t - 6 * rp;         // col-segment 0..5 (cols 6s..6s+5)

    const float* sf = reinterpret_cast<const float*>(s4);
    const int va  = rp * 72 + 6 * s;               // dword idx (row 2rp, col 6s)
    const int vaP = va - 2 + (s == 0 ? 36 : 0);    // pre-edge base (k=-2,-1)
    const int vaT = va + (s == 5 ? -36 : 0);       // tail base (k=6,7)

    // ---- pairs P[k+2] = (u[rA][(6s+k)%36], u[rB][same]), k = -2..7 ----
    f2 P[10];
#pragma unroll
    for (int k = 0; k < 2; ++k) { P[k].x = sf[vaP + k];     P[k].y = sf[vaP + k + 36]; }
#pragma unroll
    for (int k = 0; k < 6; ++k) { P[k + 2].x = sf[va + k];  P[k + 2].y = sf[va + k + 36]; }
#pragma unroll
    for (int k = 6; k < 8; ++k) { P[k + 2].x = sf[vaT + k]; P[k + 2].y = sf[vaT + k + 36]; }

    const f2 r02 = splat2(sreg[0]);
    const float* rb = sreg + 6 * s;    // rb[1..6] = reg[6s+1 .. 6s+6]

    f2 c_[6];                          // cols 6s+0..5, pair = (rowA, rowB)

    // ---- phase 1: MLP1 -> cols 3j+0 ----
#pragma unroll
    for (int J = 0; J < 2; ++J) {
        const int b = 3 * J;           // k-base for j = 2s+J
        f2 a0, a1, a2;
        mlp_a2(P[b], P[b + 2], P[b + 3], w10, b10, w11, b11, w12, b12, a0, a1, a2);
        c_[3*J + 0] = fma2(P[b + 2], splat2(rb[b + 1]), r02)
                    + fma2(a2, P[b + 4], fma2(a1, P[b + 1], a0));
    }
    // ---- phase 2: MLP2 -> cols 3j+1 ----
#pragma unroll
    for (int J = 0; J < 2; ++J) {
        const int b = 3 * J;
        f2 a0, a1, a2;
        mlp_a2(P[b + 2], P[b + 3], P[b + 5], w20, b20, w21, b21, w22, b22, a0, a1, a2);
        c_[3*J + 1] = fma2(P[b + 3], splat2(rb[b + 2]), r02)
                    + fma2(a2, P[b + 4], fma2(a1, P[b + 1], a0));
    }
    // ---- phase 3: MLP3 -> cols 3j+2 ----
#pragma unroll
    for (int J = 0; J < 2; ++J) {
        const int b = 3 * J;
        f2 d0, d1;
        mlp_b2(P[b + 2], P[b + 3], P[b + 5], P[b + 6], w30, b30, w31, b31, w32, b32, d0, d1);
        c_[3*J + 2] = fma2(P[b + 4], splat2(rb[b + 3]), r02)
                    + fma2(d1, P[b + 4], d0);
    }

    // ---- write results to the separate output tile (no WAR, no barrier) ----
    {
        float* sfo = reinterpret_cast<float*>(o4b);   // row-major [128][36]
        f2* wA = reinterpret_cast<f2*>(sfo + va);         // va even -> 8B aligned
        f2* wB = reinterpret_cast<f2*>(sfo + va + 36);
        wA[0] = mk2(c_[0].x, c_[1].x);
        wA[1] = mk2(c_[2].x, c_[3].x);
        wA[2] = mk2(c_[4].x, c_[5].x);
        wB[0] = mk2(c_[0].y, c_[1].y);
        wB[1] = mk2(c_[2].y, c_[3].y);
        wB[2] = mk2(c_[4].y, c_[5].y);
    }
    __syncthreads();                      // single block barrier: obuf ready

    // ---- flat, lane-contiguous NT stores: 3 x 1024B per wave instruction ----
    {
        fv4* __restrict__ ob = reinterpret_cast<fv4*>(out + (size_t)brow * 36);
        const fv4* sv = reinterpret_cast<const fv4*>(o4b);
#pragma unroll
        for (int k = 0; k < 3; ++k) {
            const int idx = t + k * TPB;          // 0..1151, lane-contiguous
            __builtin_nontemporal_store(sv[idx], ob + idx);
        }
    }
}

extern "C" void kernel_launch(void* const* d_in, const int* in_sizes, int n_in,
                              void* d_out, int out_size, void* d_ws, size_t ws_size,
                              hipStream_t stream)
{
    const float* u   = (const float*)d_in[1];
    const float* reg = (const float*)d_in[2];
    const float* w10 = (const float*)d_in[3];
    const float* b10 = (const float*)d_in[4];
    const float* w11 = (const float*)d_in[5];
    const float* b11 = (const float*)d_in[6];
    const float* w12 = (const float*)d_in[7];
    const float* b12 = (const float*)d_in[8];
    const float* w20 = (const float*)d_in[9];
    const float* b20 = (const float*)d_in[10];
    const float* w21 = (const float*)d_in[11];
    const float* b21 = (const float*)d_in[12];
    const float* w22 = (const float*)d_in[13];
    const float* b22 = (const float*)d_in[14];
    const float* w30 = (const float*)d_in[15];
    const float* b30 = (const float*)d_in[16];
    const float* w31 = (const float*)d_in[17];
    const float* b31 = (const float*)d_in[18];
    const float* w32 = (const float*)d_in[19];
    const float* b32 = (const float*)d_in[20];
    float* out = (float*)d_out;

    const int n = in_sizes[1] / 36;                 // 1,000,000 rows
    const int grid = (n + ROWS_PB - 1) / ROWS_PB;   // 7813 blocks (last clamped)

    hipLaunchKernelGGL(mixmodel_kernel, dim3(grid), dim3(TPB), 0, stream,
                       u, reg, w10, b10, w11, b11, w12, b12,
                       w20, b20, w21, b21, w22, b22,
                       w30, b30, w31, b31, w32, b32, out, n);
}

// Round 22
// 62.989 us; speedup vs baseline: 1.0369x; 1.0369x over previous
//
#include <hip/hip_runtime.h>

// ---------------------------------------------------------------------------
// MixModel R22: WAVE-PRIVATE everything — zero __syncthreads.
// Ladder: R10 71.1 | R16 +NT 65.3 | R17 row-pair pk 65.2 | R18 LDS-out 62.0
//   | R19 sep-obuf 2-barrier 59.8 (BEST) | R20 per-wave stage @3w 60.5
//   | R21 128-row 6-wave 65.3 (big blocks lose, again).
// Insight: 64-lane/6-segment misalignment forced block-wide coupling. With
// 60 ACTIVE LANES per wave (ROWS_PB=60): wave w, lane l<60 -> seg=60w+l,
// rp=10w+l/6, s=l%6 -> wave w consumes exactly rows [20w,20w+20) = f4
// [180w,180w+180). So each wave: 3x60-lane DMA (own region) -> own vmcnt(0)
// -> compute (lean R17 body) -> ds_write own obuf region -> lgkmcnt (wave
// lockstep => all lanes visible) -> 3x960B line-aligned NT stores. No block
// barrier at all; waves fully decorrelated (R12's concept + R17's lean body).
// Cost: 4/64 lanes idle (6%), grid 15625->16667. Last block clamped: 20-row
// overlap double-written with identical values (deterministic, NT-safe).
// Tripwires: VGPR>56 or WRITE>>141.5MB -> revert to R19 and stop.
// ---------------------------------------------------------------------------

typedef float f2 __attribute__((ext_vector_type(2)));
typedef float fv4 __attribute__((ext_vector_type(4)));

__device__ __forceinline__ f2 splat2(float x) { f2 v; v.x = x; v.y = x; return v; }
__device__ __forceinline__ f2 mk2(float a, float b) { f2 v; v.x = a; v.y = b; return v; }
__device__ __forceinline__ f2 fma2(f2 a, f2 b, f2 c) { return __builtin_elementwise_fma(a, b, c); }
__device__ __forceinline__ f2 relu2(f2 a) { return __builtin_elementwise_max(a, splat2(0.0f)); }

// Packed MLP 3->3->6->3 (pair-axis = 2 rows).
__device__ __forceinline__ void mlp_a2(f2 x0, f2 x1, f2 x2,
                                       const float* __restrict__ w0, const float* __restrict__ b0,
                                       const float* __restrict__ w1, const float* __restrict__ b1,
                                       const float* __restrict__ w2, const float* __restrict__ b2,
                                       f2& o0, f2& o1, f2& o2)
{
    f2 h0[3];
#pragma unroll
    for (int q = 0; q < 3; ++q) {
        f2 a = fma2(x0, splat2(w0[q*3+0]), splat2(b0[q]));
        a = fma2(x1, splat2(w0[q*3+1]), a);
        a = fma2(x2, splat2(w0[q*3+2]), a);
        h0[q] = relu2(a);
    }
    f2 h1[6];
#pragma unroll
    for (int q = 0; q < 6; ++q) {
        f2 a = fma2(h0[0], splat2(w1[q*3+0]), splat2(b1[q]));
        a = fma2(h0[1], splat2(w1[q*3+1]), a);
        a = fma2(h0[2], splat2(w1[q*3+2]), a);
        h1[q] = relu2(a);
    }
    f2 t[3];
#pragma unroll
    for (int q = 0; q < 3; ++q) {
        f2 a = fma2(h1[0], splat2(w2[q*6+0]), splat2(b2[q]));
#pragma unroll
        for (int i = 1; i < 6; ++i) a = fma2(h1[i], splat2(w2[q*6+i]), a);
        t[q] = a;
    }
    o0 = t[0]; o1 = t[1]; o2 = t[2];
}

// Packed MLP 4->4->6->2 (pair-axis = 2 rows).
__device__ __forceinline__ void mlp_b2(f2 x0, f2 x1, f2 x2, f2 x3,
                                       const float* __restrict__ w0, const float* __restrict__ b0,
                                       const float* __restrict__ w1, const float* __restrict__ b1,
                                       const float* __restrict__ w2, const float* __restrict__ b2,
                                       f2& o0, f2& o1)
{
    f2 h0[4];
#pragma unroll
    for (int q = 0; q < 4; ++q) {
        f2 a = fma2(x0, splat2(w0[q*4+0]), splat2(b0[q]));
        a = fma2(x1, splat2(w0[q*4+1]), a);
        a = fma2(x2, splat2(w0[q*4+2]), a);
        a = fma2(x3, splat2(w0[q*4+3]), a);
        h0[q] = relu2(a);
    }
    f2 h1[6];
#pragma unroll
    for (int q = 0; q < 6; ++q) {
        f2 a = fma2(h0[0], splat2(w1[q*4+0]), splat2(b1[q]));
        a = fma2(h0[1], splat2(w1[q*4+1]), a);
        a = fma2(h0[2], splat2(w1[q*4+2]), a);
        a = fma2(h0[3], splat2(w1[q*4+3]), a);
        h1[q] = relu2(a);
    }
    f2 t[2];
#pragma unroll
    for (int q = 0; q < 2; ++q) {
        f2 a = fma2(h1[0], splat2(w2[q*6+0]), splat2(b2[q]));
#pragma unroll
        for (int i = 1; i < 6; ++i) a = fma2(h1[i], splat2(w2[q*6+i]), a);
        t[q] = a;
    }
    o0 = t[0]; o1 = t[1];
}

#define ROWS_PB 60
#define TPB 192   // 3 waves; wave w, lanes 0..59 -> segs 60w..60w+59

__global__ __launch_bounds__(TPB) void mixmodel_kernel(
    const float* __restrict__ u, const float* __restrict__ reg,
    const float* __restrict__ w10, const float* __restrict__ b10,
    const float* __restrict__ w11, const float* __restrict__ b11,
    const float* __restrict__ w12, const float* __restrict__ b12,
    const float* __restrict__ w20, const float* __restrict__ b20,
    const float* __restrict__ w21, const float* __restrict__ b21,
    const float* __restrict__ w22, const float* __restrict__ b22,
    const float* __restrict__ w30, const float* __restrict__ b30,
    const float* __restrict__ w31, const float* __restrict__ b31,
    const float* __restrict__ w32, const float* __restrict__ b32,
    float* __restrict__ out, int n)
{
    __shared__ float4 s4[ROWS_PB * 9];    // 8640 B input u-tile ([60][36]f)
    __shared__ float4 o4b[ROWS_PB * 9];   // 8640 B output tile
    __shared__ float  sreg[37];           // written redundantly by each wave

    // clamp: last block re-covers earlier rows; overlap computed twice with
    // identical values -> benign (deterministic, NT-safe).
    const int brow = min((int)blockIdx.x * ROWS_PB, n - ROWS_PB);
    const int wv   = threadIdx.x >> 6;    // wave 0..2
    const int lane = threadIdx.x & 63;

    if (lane < 60) {
        // ---- wave-private DMA: wave wv stages f4 [180wv, 180wv+180) ----
        {
            const float4* __restrict__ g = reinterpret_cast<const float4*>(u + (size_t)brow * 36);
#pragma unroll
            for (int k = 0; k < 3; ++k) {
                const int base = 180 * wv + 60 * k;   // f4 units, wave-uniform
                __builtin_amdgcn_global_load_lds(
                    (const __attribute__((address_space(1))) void*)(g + base + lane),
                    (__attribute__((address_space(3))) void*)(s4 + base),
                    16, 0, 0);
            }
        }
        if (lane < 37) sreg[lane] = reg[lane];   // redundant per wave, same vals

        // wave-local drain; no block barrier anywhere in this kernel
        asm volatile("s_waitcnt vmcnt(0) lgkmcnt(0)" ::: "memory");
        __builtin_amdgcn_sched_barrier(0);

        const int rp = 10 * wv + lane / 6;    // row-pair (rows 2rp, 2rp+1)
        const int s  = lane % 6;              // col-segment (cols 6s..6s+5)

        const float* sf = reinterpret_cast<const float*>(s4);
        const int va  = rp * 72 + 6 * s;               // dword idx (row 2rp, col 6s)
        const int vaP = va - 2 + (s == 0 ? 36 : 0);    // pre-edge base (k=-2,-1)
        const int vaT = va + (s == 5 ? -36 : 0);       // tail base (k=6,7)

        // ---- pairs P[k+2] = (u[rA][(6s+k)%36], u[rB][same]), k=-2..7 ----
        f2 P[10];
#pragma unroll
        for (int k = 0; k < 2; ++k) { P[k].x = sf[vaP + k];     P[k].y = sf[vaP + k + 36]; }
#pragma unroll
        for (int k = 0; k < 6; ++k) { P[k + 2].x = sf[va + k];  P[k + 2].y = sf[va + k + 36]; }
#pragma unroll
        for (int k = 6; k < 8; ++k) { P[k + 2].x = sf[vaT + k]; P[k + 2].y = sf[vaT + k + 36]; }

        const f2 r02 = splat2(sreg[0]);
        const float* rb = sreg + 6 * s;

        f2 c_[6];   // cols 6s+0..5, pair = (rowA, rowB)

        // ---- phase 1: MLP1 -> cols 3j+0 ----
#pragma unroll
        for (int J = 0; J < 2; ++J) {
            const int b = 3 * J;
            f2 a0, a1, a2;
            mlp_a2(P[b], P[b + 2], P[b + 3], w10, b10, w11, b11, w12, b12, a0, a1, a2);
            c_[3*J + 0] = fma2(P[b + 2], splat2(rb[b + 1]), r02)
                        + fma2(a2, P[b + 4], fma2(a1, P[b + 1], a0));
        }
        // ---- phase 2: MLP2 -> cols 3j+1 ----
#pragma unroll
        for (int J = 0; J < 2; ++J) {
            const int b = 3 * J;
            f2 a0, a1, a2;
            mlp_a2(P[b + 2], P[b + 3], P[b + 5], w20, b20, w21, b21, w22, b22, a0, a1, a2);
            c_[3*J + 1] = fma2(P[b + 3], splat2(rb[b + 2]), r02)
                        + fma2(a2, P[b + 4], fma2(a1, P[b + 1], a0));
        }
        // ---- phase 3: MLP3 -> cols 3j+2 ----
#pragma unroll
        for (int J = 0; J < 2; ++J) {
            const int b = 3 * J;
            f2 d0, d1;
            mlp_b2(P[b + 2], P[b + 3], P[b + 5], P[b + 6], w30, b30, w31, b31, w32, b32, d0, d1);
            c_[3*J + 2] = fma2(P[b + 4], splat2(rb[b + 3]), r02)
                        + fma2(d1, P[b + 4], d0);
        }

        // ---- write results into the wave's own obuf region ----
        {
            float* sfo = reinterpret_cast<float*>(o4b);   // row-major [60][36]
            f2* wA = reinterpret_cast<f2*>(sfo + va);         // va even -> 8B aligned
            f2* wB = reinterpret_cast<f2*>(sfo + va + 36);
            wA[0] = mk2(c_[0].x, c_[1].x);
            wA[1] = mk2(c_[2].x, c_[3].x);
            wA[2] = mk2(c_[4].x, c_[5].x);
            wB[0] = mk2(c_[0].y, c_[1].y);
            wB[1] = mk2(c_[2].y, c_[3].y);
            wB[2] = mk2(c_[4].y, c_[5].y);
        }
        // wave lockstep: once this wave's ds_writes are drained, ALL its
        // lanes' data is visible — no cross-wave reads, so no barrier.
        asm volatile("s_waitcnt lgkmcnt(0)" ::: "memory");
        __builtin_amdgcn_sched_barrier(0);

        // ---- wave-private NT tail: 3 x 960B line-aligned chunks ----
        {
            fv4* __restrict__ ob = reinterpret_cast<fv4*>(out + (size_t)brow * 36);
            const fv4* sv = reinterpret_cast<const fv4*>(o4b);
#pragma unroll
            for (int k = 0; k < 3; ++k) {
                const int idx = 180 * wv + 60 * k + lane;   // within own region
                __builtin_nontemporal_store(sv[idx], ob + idx);
            }
        }
    }
}

extern "C" void kernel_launch(void* const* d_in, const int* in_sizes, int n_in,
                              void* d_out, int out_size, void* d_ws, size_t ws_size,
                              hipStream_t stream)
{
    const float* u   = (const float*)d_in[1];
    const float* reg = (const float*)d_in[2];
    const float* w10 = (const float*)d_in[3];
    const float* b10 = (const float*)d_in[4];
    const float* w11 = (const float*)d_in[5];
    const float* b11 = (const float*)d_in[6];
    const float* w12 = (const float*)d_in[7];
    const float* b12 = (const float*)d_in[8];
    const float* w20 = (const float*)d_in[9];
    const float* b20 = (const float*)d_in[10];
    const float* w21 = (const float*)d_in[11];
    const float* b21 = (const float*)d_in[12];
    const float* w22 = (const float*)d_in[13];
    const float* b22 = (const float*)d_in[14];
    const float* w30 = (const float*)d_in[15];
    const float* b30 = (const float*)d_in[16];
    const float* w31 = (const float*)d_in[17];
    const float* b31 = (const float*)d_in[18];
    const float* w32 = (const float*)d_in[19];
    const float* b32 = (const float*)d_in[20];
    float* out = (float*)d_out;

    const int n = in_sizes[1] / 36;                 // 1,000,000 rows
    const int grid = (n + ROWS_PB - 1) / ROWS_PB;   // 16667 blocks (last clamped)

    hipLaunchKernelGGL(mixmodel_kernel, dim3(grid), dim3(TPB), 0, stream,
                       u, reg, w10, b10, w11, b11, w12, b12,
                       w20, b20, w21, b21, w22, b22,
                       w30, b30, w31, b31, w32, b32, out, n);
}

// Round 23
// 59.763 us; speedup vs baseline: 1.0929x; 1.0540x over previous
//
#include <hip/hip_runtime.h>

// ---------------------------------------------------------------------------
// MixModel R23 = R19 EXACTLY + full streaming stores (nt sc0 sc1) so the
// output stream bypasses L3 too, keeping u L3-resident (FETCH 70MB -> ~0).
// Ladder: R10 71.1 | R16 +NT 65.3 | R17 row-pair pk 65.2 | R18 LDS-out 62.0
//   | R19 sep-obuf 2-barrier 59.8 (BEST) | R20 per-wave stage 60.5 (neutral)
//   | R21 128-row 6-wave 65.3 | R22 wave-private 0-barrier 63.0.
// Sync structure & geometry exhausted; last reducible term is 70MB u
// re-fetch from HBM (out stream evicts u from L3; builtin NT only sets nt,
// gfx950 full streaming needs sc0 sc1 nt — write-through, no allocation).
// Tripwires: FETCH unchanged or dur >= 59.8 -> revert to R19 as final.
// ---------------------------------------------------------------------------

typedef float f2 __attribute__((ext_vector_type(2)));
typedef float fv4 __attribute__((ext_vector_type(4)));

__device__ __forceinline__ f2 splat2(float x) { f2 v; v.x = x; v.y = x; return v; }
__device__ __forceinline__ f2 mk2(float a, float b) { f2 v; v.x = a; v.y = b; return v; }
__device__ __forceinline__ f2 fma2(f2 a, f2 b, f2 c) { return __builtin_elementwise_fma(a, b, c); }
__device__ __forceinline__ f2 relu2(f2 a) { return __builtin_elementwise_max(a, splat2(0.0f)); }

// Packed MLP 3->3->6->3 (pair-axis = 2 rows).
__device__ __forceinline__ void mlp_a2(f2 x0, f2 x1, f2 x2,
                                       const float* __restrict__ w0, const float* __restrict__ b0,
                                       const float* __restrict__ w1, const float* __restrict__ b1,
                                       const float* __restrict__ w2, const float* __restrict__ b2,
                                       f2& o0, f2& o1, f2& o2)
{
    f2 h0[3];
#pragma unroll
    for (int q = 0; q < 3; ++q) {
        f2 a = fma2(x0, splat2(w0[q*3+0]), splat2(b0[q]));
        a = fma2(x1, splat2(w0[q*3+1]), a);
        a = fma2(x2, splat2(w0[q*3+2]), a);
        h0[q] = relu2(a);
    }
    f2 h1[6];
#pragma unroll
    for (int q = 0; q < 6; ++q) {
        f2 a = fma2(h0[0], splat2(w1[q*3+0]), splat2(b1[q]));
        a = fma2(h0[1], splat2(w1[q*3+1]), a);
        a = fma2(h0[2], splat2(w1[q*3+2]), a);
        h1[q] = relu2(a);
    }
    f2 t[3];
#pragma unroll
    for (int q = 0; q < 3; ++q) {
        f2 a = fma2(h1[0], splat2(w2[q*6+0]), splat2(b2[q]));
#pragma unroll
        for (int i = 1; i < 6; ++i) a = fma2(h1[i], splat2(w2[q*6+i]), a);
        t[q] = a;
    }
    o0 = t[0]; o1 = t[1]; o2 = t[2];
}

// Packed MLP 4->4->6->2 (pair-axis = 2 rows).
__device__ __forceinline__ void mlp_b2(f2 x0, f2 x1, f2 x2, f2 x3,
                                       const float* __restrict__ w0, const float* __restrict__ b0,
                                       const float* __restrict__ w1, const float* __restrict__ b1,
                                       const float* __restrict__ w2, const float* __restrict__ b2,
                                       f2& o0, f2& o1)
{
    f2 h0[4];
#pragma unroll
    for (int q = 0; q < 4; ++q) {
        f2 a = fma2(x0, splat2(w0[q*4+0]), splat2(b0[q]));
        a = fma2(x1, splat2(w0[q*4+1]), a);
        a = fma2(x2, splat2(w0[q*4+2]), a);
        a = fma2(x3, splat2(w0[q*4+3]), a);
        h0[q] = relu2(a);
    }
    f2 h1[6];
#pragma unroll
    for (int q = 0; q < 6; ++q) {
        f2 a = fma2(h0[0], splat2(w1[q*4+0]), splat2(b1[q]));
        a = fma2(h0[1], splat2(w1[q*4+1]), a);
        a = fma2(h0[2], splat2(w1[q*4+2]), a);
        a = fma2(h0[3], splat2(w1[q*4+3]), a);
        h1[q] = relu2(a);
    }
    f2 t[2];
#pragma unroll
    for (int q = 0; q < 2; ++q) {
        f2 a = fma2(h1[0], splat2(w2[q*6+0]), splat2(b2[q]));
#pragma unroll
        for (int i = 1; i < 6; ++i) a = fma2(h1[i], splat2(w2[q*6+i]), a);
        t[q] = a;
    }
    o0 = t[0]; o1 = t[1];
}

#define ROWS_PB 64
#define TPB 192   // 3 waves; 64 rows = 32 row-pairs x 6 col-segments = 192

__global__ __launch_bounds__(TPB) void mixmodel_kernel(
    const float* __restrict__ u, const float* __restrict__ reg,
    const float* __restrict__ w10, const float* __restrict__ b10,
    const float* __restrict__ w11, const float* __restrict__ b11,
    const float* __restrict__ w12, const float* __restrict__ b12,
    const float* __restrict__ w20, const float* __restrict__ b20,
    const float* __restrict__ w21, const float* __restrict__ b21,
    const float* __restrict__ w22, const float* __restrict__ b22,
    const float* __restrict__ w30, const float* __restrict__ b30,
    const float* __restrict__ w31, const float* __restrict__ b31,
    const float* __restrict__ w32, const float* __restrict__ b32,
    float* __restrict__ out, int n)
{
    __shared__ float4 s4[ROWS_PB * 9];    // 9216 B input u-tile
    __shared__ float4 o4b[ROWS_PB * 9];   // 9216 B output tile
    __shared__ float  sreg[37];

    const int brow = blockIdx.x * ROWS_PB;

    // ---- stage 64-row u-tile via DMA (identical to R19) ----
    {
        const float4* __restrict__ g = reinterpret_cast<const float4*>(u + (size_t)brow * 36);
        const int wid  = threadIdx.x >> 6;
        const int lane = threadIdx.x & 63;
#pragma unroll
        for (int w = 0; w < 3; ++w) {
            const int base = w * TPB + wid * 64;   // f4 units, wave-uniform
            __builtin_amdgcn_global_load_lds(
                (const __attribute__((address_space(1))) void*)(g + base + lane),
                (__attribute__((address_space(3))) void*)(s4 + base),
                16, 0, 0);
        }
    }
    if (threadIdx.x < 37) sreg[threadIdx.x] = reg[threadIdx.x];
    asm volatile("s_waitcnt vmcnt(0)" ::: "memory");
    __syncthreads();                      // barrier 1: tile ready

    const int t  = threadIdx.x;
    const int rp = t / 6;              // row-pair 0..31 (rows 2rp, 2rp+1)
    const int s  = t - 6 * rp;         // col-segment 0..5 (cols 6s..6s+5)

    const float* sf = reinterpret_cast<const float*>(s4);
    const int va  = rp * 72 + 6 * s;               // dword idx (row 2rp, col 6s)
    const int vaP = va - 2 + (s == 0 ? 36 : 0);    // pre-edge base (k=-2,-1)
    const int vaT = va + (s == 5 ? -36 : 0);       // tail base (k=6,7)

    // ---- pairs P[k+2] = (u[rA][(6s+k)%36], u[rB][same]), k = -2..7 ----
    f2 P[10];
#pragma unroll
    for (int k = 0; k < 2; ++k) { P[k].x = sf[vaP + k];     P[k].y = sf[vaP + k + 36]; }
#pragma unroll
    for (int k = 0; k < 6; ++k) { P[k + 2].x = sf[va + k];  P[k + 2].y = sf[va + k + 36]; }
#pragma unroll
    for (int k = 6; k < 8; ++k) { P[k + 2].x = sf[vaT + k]; P[k + 2].y = sf[vaT + k + 36]; }

    const f2 r02 = splat2(sreg[0]);
    const float* rb = sreg + 6 * s;    // rb[1..6] = reg[6s+1 .. 6s+6]

    f2 c_[6];                          // cols 6s+0..5, pair = (rowA, rowB)

    // ---- phase 1: MLP1 -> cols 3j+0 ----
#pragma unroll
    for (int J = 0; J < 2; ++J) {
        const int b = 3 * J;           // k-base for j = 2s+J
        f2 a0, a1, a2;
        mlp_a2(P[b], P[b + 2], P[b + 3], w10, b10, w11, b11, w12, b12, a0, a1, a2);
        c_[3*J + 0] = fma2(P[b + 2], splat2(rb[b + 1]), r02)
                    + fma2(a2, P[b + 4], fma2(a1, P[b + 1], a0));
    }
    // ---- phase 2: MLP2 -> cols 3j+1 ----
#pragma unroll
    for (int J = 0; J < 2; ++J) {
        const int b = 3 * J;
        f2 a0, a1, a2;
        mlp_a2(P[b + 2], P[b + 3], P[b + 5], w20, b20, w21, b21, w22, b22, a0, a1, a2);
        c_[3*J + 1] = fma2(P[b + 3], splat2(rb[b + 2]), r02)
                    + fma2(a2, P[b + 4], fma2(a1, P[b + 1], a0));
    }
    // ---- phase 3: MLP3 -> cols 3j+2 ----
#pragma unroll
    for (int J = 0; J < 2; ++J) {
        const int b = 3 * J;
        f2 d0, d1;
        mlp_b2(P[b + 2], P[b + 3], P[b + 5], P[b + 6], w30, b30, w31, b31, w32, b32, d0, d1);
        c_[3*J + 2] = fma2(P[b + 4], splat2(rb[b + 3]), r02)
                    + fma2(d1, P[b + 4], d0);
    }

    // ---- write results to the separate output tile (no WAR, no barrier) ----
    {
        float* sfo = reinterpret_cast<float*>(o4b);   // row-major [64][36]
        f2* wA = reinterpret_cast<f2*>(sfo + va);         // va even -> 8B aligned
        f2* wB = reinterpret_cast<f2*>(sfo + va + 36);
        wA[0] = mk2(c_[0].x, c_[1].x);
        wA[1] = mk2(c_[2].x, c_[3].x);
        wA[2] = mk2(c_[4].x, c_[5].x);
        wB[0] = mk2(c_[0].y, c_[1].y);
        wB[1] = mk2(c_[2].y, c_[3].y);
        wB[2] = mk2(c_[4].y, c_[5].y);
    }
    __syncthreads();                      // barrier 2: output tile complete

    // ---- flat, lane-contiguous STREAMING stores (nt sc0 sc1: no cache
    // allocation at any level — keep u resident in L3) ----
    {
        fv4* __restrict__ ob = reinterpret_cast<fv4*>(out + (size_t)brow * 36);
        const fv4* sv = reinterpret_cast<const fv4*>(o4b);
#pragma unroll
        for (int k = 0; k < 3; ++k) {
            const int idx = t + k * TPB;          // 0..575, lane-contiguous
            fv4 v = sv[idx];
            asm volatile("global_store_dwordx4 %0, %1, off nt sc0 sc1"
                         :: "v"(ob + idx), "v"(v) : "memory");
        }
    }
}

extern "C" void kernel_launch(void* const* d_in, const int* in_sizes, int n_in,
                              void* d_out, int out_size, void* d_ws, size_t ws_size,
                              hipStream_t stream)
{
    const float* u   = (const float*)d_in[1];
    const float* reg = (const float*)d_in[2];
    const float* w10 = (const float*)d_in[3];
    const float* b10 = (const float*)d_in[4];
    const float* w11 = (const float*)d_in[5];
    const float* b11 = (const float*)d_in[6];
    const float* w12 = (const float*)d_in[7];
    const float* b12 = (const float*)d_in[8];
    const float* w20 = (const float*)d_in[9];
    const float* b20 = (const float*)d_in[10];
    const float* w21 = (const float*)d_in[11];
    const float* b21 = (const float*)d_in[12];
    const float* w22 = (const float*)d_in[13];
    const float* b22 = (const float*)d_in[14];
    const float* w30 = (const float*)d_in[15];
    const float* b30 = (const float*)d_in[16];
    const float* w31 = (const float*)d_in[17];
    const float* b31 = (const float*)d_in[18];
    const float* w32 = (const float*)d_in[19];
    const float* b32 = (const float*)d_in[20];
    float* out = (float*)d_out;

    const int n = in_sizes[1] / 36;            // 1,000,000 rows; 64 | n exactly
    const int grid = (n + ROWS_PB - 1) / ROWS_PB;   // 15625 full tiles

    hipLaunchKernelGGL(mixmodel_kernel, dim3(grid), dim3(TPB), 0, stream,
                       u, reg, w10, b10, w11, b11, w12, b12,
                       w20, b20, w21, b21, w22, b22,
                       w30, b30, w31, b31, w32, b32, out, n);
}